// Round 6
// baseline (395.450 us; speedup 1.0000x reference)
//
#include <hip/hip_runtime.h>
#include <hip/hip_bf16.h>

// AttentiveGraph: B=4, N=10000, E=160000, C=F=128, 3 iterations.
// R16 = R15 resubmitted (previous round's bench died to container-acquisition
// infra failure, not a kernel result; OOB audit found no defect).
// R15: binding constraint is VMEM instruction/request COUNT. Gather geometry:
// lane=(q=lane>>4, p=lane&15); ONE global_load_dwordx4 fetches FOUR edge rows
// (edge-slot q's channels p*4..p*4+3 per lane).
//   per 8-edge group: 2 gathers + 2 coalesced index loads (ed[e+q])
//   vs R14's 8 gathers + 8 scalar index loads + 8 readfirstlane.
// VMEM instrs 4x down (5.1M -> 1.3M/dispatch), VALU/edge 3.5 -> ~2.3 ops.
// 8 independent fma_mix chains/lane (4ch x {s1,s2}); 2-step __shfl_xor
// butterfly (16,32) reduces the 4 edge slots; q==0 lanes write uint4.
// CSR pad-to-8 + sentinel zero rows (R14) kept. Ping-pong 2-deep kept.
// Fused GEMM kernels, gat/lgsa formats, eah staging unchanged.

#define BATCH 4
#define NNODE 10000
#define NEDGE 160000
#define TWOE  (2*NEDGE)
#define MROWS (BATCH*NNODE)   // 40000
#define NCHUNK 64
#define CHUNKE (NEDGE/NCHUNK) // 2500
#define PADN  10240
#define EDPAD (TWOE + 8*NNODE) // 400000: padded edge capacity per batch

typedef unsigned short u16;
typedef unsigned int   u32;
typedef __attribute__((ext_vector_type(8))) short bf16x8_t;
typedef __attribute__((ext_vector_type(4))) float f32x4_t;

__device__ __forceinline__ float b2f(u16 h){ return __uint_as_float(((u32)h) << 16); }
__device__ __forceinline__ u16 f2bf(float f){
  u32 u = __float_as_uint(f);
  return (u16)((u + 0x7fffu + ((u >> 16) & 1u)) >> 16);   // RNE
}
__device__ __forceinline__ float fast_tanh(float x){
  float e = __expf(2.0f * x);
  return fmaf(-2.0f, __builtin_amdgcn_rcpf(e + 1.0f), 1.0f);
}

// ---------------- storage dtype probe (fp32 vs bf16 storage) ------------------
__global__ void detect_dtype(const u32* __restrict__ objw, int* __restrict__ flag){
  __shared__ int zc, hc;
  if (threadIdx.x == 0){ zc = 0; hc = 0; }
  __syncthreads();
  int z = 0, h = 0;
  for (int i = threadIdx.x; i < 1024; i += 256){
    u32 lo = objw[i] & 0xffffu;
    if (lo == 0) z++;
    if (((lo >> 7) & 0xffu) >= 160u) h++;
  }
  atomicAdd(&zc, z); atomicAdd(&hc, h);
  __syncthreads();
  if (threadIdx.x == 0) *flag = (hc > 0 || zc > 512) ? 1 : 0;   // 1 = fp32 storage
}

// Wt[m][c*128+k] = W_m[k*128+c]; tail block converts biases.
__global__ void prep_weights(const void* __restrict__ Wo, const void* __restrict__ Wa,
                             const void* __restrict__ Wla, const void* __restrict__ Wl,
                             const void* __restrict__ ab, const void* __restrict__ sb,
                             const int* __restrict__ flag, u16* __restrict__ Wt,
                             float* __restrict__ biasf){
  int idx = blockIdx.x * 256 + threadIdx.x;
  bool f = (*flag != 0);
  if (idx < 65536){
    int m = idx >> 14, k = (idx >> 7) & 127, c = idx & 127;
    const void* src = (m == 0) ? Wo : (m == 1) ? Wa : (m == 2) ? Wla : Wl;
    u16 h = f ? f2bf(((const float*)src)[k * 128 + c]) : ((const u16*)src)[k * 128 + c];
    Wt[m * 16384 + c * 128 + k] = h;
  } else {
    int t = idx - 65536;
    const void* src = (t < 128) ? sb : ab;
    int i = t & 127;
    biasf[t] = f ? ((const float*)src)[i] : b2f(((const u16*)src)[i]);
  }
}

// ---------------- CSR build: 3-phase chunked histogram ------------------------
__device__ __forceinline__ void chunk_of(int blk, int& b, int& c){
  int xcd = blk & 7;
  b = xcd >> 1;
  c = ((blk >> 3) << 1) | (xcd & 1);           // 0..63
}

__global__ void __launch_bounds__(256) csr_hist(const int* __restrict__ conn,
                                                u16* __restrict__ partial){
  int b, c; chunk_of(blockIdx.x, b, c);
  __shared__ u32 hist[NNODE];
  for (int n = threadIdx.x; n < NNODE; n += 256) hist[n] = 0;
  __syncthreads();
  const int2* cp = (const int2*)conn + (size_t)b * NEDGE + c * CHUNKE;
  for (int i = threadIdx.x; i < CHUNKE; i += 256){
    int2 e = cp[i];
    atomicAdd(&hist[e.x], 1);
    atomicAdd(&hist[e.y], 1);
  }
  __syncthreads();
  u16* prow = partial + (size_t)(b * NCHUNK + c) * PADN;
  for (int n = threadIdx.x; n < NNODE; n += 256) prow[n] = (u16)hist[n];
}

// prefix over chunks per node (true offsets stored back), then block-scan of
// PADDED row lengths (multiple of 8); deg[] keeps true degree for pad_fill.
__global__ void __launch_bounds__(256) csr_colscan(u16* __restrict__ partial,
    int* __restrict__ row_start, int* __restrict__ bsum, int* __restrict__ deg){
  int b = blockIdx.x / 40, w = blockIdx.x % 40;
  int n = w * 256 + threadIdx.x;
  u32 run = 0;
  if (n < NNODE){
    #pragma unroll 8
    for (int c = 0; c < NCHUNK; c++){
      size_t idx = (size_t)(b * NCHUNK + c) * PADN + n;
      u32 v = partial[idx];
      partial[idx] = (u16)run;
      run += v;
    }
  }
  u32 pad = (run + 7u) & ~7u;
  __shared__ u32 buf[256];
  buf[threadIdx.x] = pad;
  __syncthreads();
  for (int off = 1; off < 256; off <<= 1){
    u32 x = (threadIdx.x >= (unsigned)off) ? buf[threadIdx.x - off] : 0;
    __syncthreads();
    buf[threadIdx.x] += x;
    __syncthreads();
  }
  u32 incl = buf[threadIdx.x];
  if (n < NNODE){
    row_start[b * (NNODE + 1) + n] = (int)(incl - pad);  // window-local padded
    deg[b * NNODE + n] = (int)run;
  }
  if (threadIdx.x == 255) bsum[blockIdx.x] = (int)incl;
}

__global__ void scanB(const int* __restrict__ bsum, int* __restrict__ boff,
                      int* __restrict__ row_start){
  __shared__ int s[160];
  if (threadIdx.x < 160) s[threadIdx.x] = bsum[threadIdx.x];
  __syncthreads();
  if (threadIdx.x < 160){
    int b = threadIdx.x / 40, j = threadIdx.x % 40;
    int off = 0;
    for (int q = b * 40; q < b * 40 + j; q++) off += s[q];
    boff[threadIdx.x] = off;
  }
  if (threadIdx.x < BATCH){
    int tot = 0;
    for (int q = threadIdx.x * 40; q < threadIdx.x * 40 + 40; q++) tot += s[q];
    row_start[threadIdx.x * (NNODE + 1) + NNODE] = tot;   // padded batch total
  }
}

__global__ void scanC(int* __restrict__ row_start, const int* __restrict__ boff){
  int b = blockIdx.x / 40, j = blockIdx.x % 40;
  int n = j * 256 + threadIdx.x;
  if (n < NNODE) row_start[b * (NNODE + 1) + n] += boff[blockIdx.x];
}

__global__ void __launch_bounds__(256) csr_fill(const int* __restrict__ conn,
    const u16* __restrict__ partial, const int* __restrict__ row_start,
    int* __restrict__ edge_dst){
  int b, c; chunk_of(blockIdx.x, b, c);
  __shared__ u32 cur[NNODE];
  const u16* prow = partial + (size_t)(b * NCHUNK + c) * PADN;
  const int* rs = row_start + b * (NNODE + 1);
  for (int n = threadIdx.x; n < NNODE; n += 256) cur[n] = (u32)rs[n] + prow[n];
  __syncthreads();
  const int2* cp = (const int2*)conn + (size_t)b * NEDGE + c * CHUNKE;
  int* edb = edge_dst + (size_t)b * EDPAD;
  for (int i = threadIdx.x; i < CHUNKE; i += 256){
    int2 e = cp[i];
    u32 p1 = atomicAdd(&cur[e.x], 1); edb[p1] = e.y;
    u32 p2 = atomicAdd(&cur[e.y], 1); edb[p2] = e.x;
  }
}

// fill pad slots [rs[n]+deg, rs[n+1]) with the batch's sentinel local index.
// Sentinel local d maps to global gat row 40000+b (a dedicated zero row):
// d = 40000 + b - b*NNODE = 40000 - 9999*b.
__global__ void pad_fill(const int* __restrict__ row_start,
                         const int* __restrict__ deg, int* __restrict__ edge_dst){
  int b = blockIdx.x / 40, j = blockIdx.x % 40;
  int n = j * 256 + threadIdx.x;
  if (n >= NNODE) return;
  const int* rs = row_start + b * (NNODE + 1);
  int s = rs[n] + deg[b * NNODE + n];
  int epad = rs[n + 1];
  int sent = 40000 - 9999 * b;
  int* edb = edge_dst + (size_t)b * EDPAD;
  for (int p = s; p < epad; p++) edb[p] = sent;
}

// zero the 4 sentinel rows (global rows 40000..40003) in both gat halves.
__global__ void zero_sent(u32* __restrict__ g0, u32* __restrict__ g1){
  size_t base = (size_t)MROWS * 64;
  g0[base + threadIdx.x] = 0;
  g1[base + threadIdx.x] = 0;
}

// ---------------- MFMA helpers (wave = 16 rows x 64 cols) ---------------------
__device__ __forceinline__ void gemm_tile4(const u16* __restrict__ arow,
    const u16* __restrict__ wt, int lm, int lq, int cofs, f32x4_t acc[4]){
  #pragma unroll
  for (int ks = 0; ks < 4; ks++){
    bf16x8_t a = *(const bf16x8_t*)(arow + ks * 32);
    #pragma unroll
    for (int nb = 0; nb < 4; nb++){
      bf16x8_t bfr = *(const bf16x8_t*)(wt + (cofs + nb * 16 + lm) * 128 + ks * 32 + lq * 8);
      acc[nb] = __builtin_amdgcn_mfma_f32_16x16x32_bf16(a, bfr, acc[nb], 0, 0, 0);
    }
  }
}

// A-frag from packed lgsa (lg = low u16 of each u32). Lrow = row base ONLY.
__device__ __forceinline__ void gemm_tile4_packed(const u32* __restrict__ Lrow,
    const u16* __restrict__ wt, int lm, int lq, int cofs, f32x4_t acc[4]){
  #pragma unroll
  for (int ks = 0; ks < 4; ks++){
    uint4 wa = *(const uint4*)(Lrow + ks * 32 + lq * 8);
    uint4 wb = *(const uint4*)(Lrow + ks * 32 + lq * 8 + 4);
    bf16x8_t a;
    a[0] = (short)wa.x; a[1] = (short)wa.y; a[2] = (short)wa.z; a[3] = (short)wa.w;
    a[4] = (short)wb.x; a[5] = (short)wb.y; a[6] = (short)wb.z; a[7] = (short)wb.w;
    #pragma unroll
    for (int nb = 0; nb < 4; nb++){
      bf16x8_t bfr = *(const bf16x8_t*)(wt + (cofs + nb * 16 + lm) * 128 + ks * 32 + lq * 8);
      acc[nb] = __builtin_amdgcn_mfma_f32_16x16x32_bf16(a, bfr, acc[nb], 0, 0, 0);
    }
  }
}

// phase 2: states tile (LDS, A-layout) -> gat {S fp16 hi | EL fp16 lo} u32
// stores (full-line) + ea fp16 into LDS tile eat (coalesced global store done
// by caller).
__device__ __forceinline__ void phase2_awlaw4(const u16* __restrict__ ldstile,
    const u16* __restrict__ Wt, const float* __restrict__ biasf,
    int lm, int lq, int cofs, int r0, _Float16* __restrict__ eat,
    u32* __restrict__ ghw){
  const u16* Wta  = Wt + 16384;
  const u16* Wtla = Wt + 32768;
  const u16* ldsrow = ldstile + lm * 136 + lq * 8;
  f32x4_t accA[4], accL[4];
  #pragma unroll
  for (int i = 0; i < 4; i++){ accA[i] = (f32x4_t){0.f,0.f,0.f,0.f}; accL[i] = (f32x4_t){0.f,0.f,0.f,0.f}; }
  #pragma unroll
  for (int ks = 0; ks < 4; ks++){
    bf16x8_t a = *(const bf16x8_t*)(ldsrow + ks * 32);
    #pragma unroll
    for (int nb = 0; nb < 4; nb++){
      bf16x8_t ba = *(const bf16x8_t*)(Wta  + (cofs + nb * 16 + lm) * 128 + ks * 32 + lq * 8);
      bf16x8_t bl = *(const bf16x8_t*)(Wtla + (cofs + nb * 16 + lm) * 128 + ks * 32 + lq * 8);
      accA[nb] = __builtin_amdgcn_mfma_f32_16x16x32_bf16(a, ba, accA[nb], 0, 0, 0);
      accL[nb] = __builtin_amdgcn_mfma_f32_16x16x32_bf16(a, bl, accL[nb], 0, 0, 0);
    }
  }
  #pragma unroll
  for (int nb = 0; nb < 4; nb++){
    int col = cofs + nb * 16 + lm;
    float bb = biasf[128 + col];
    #pragma unroll
    for (int i = 0; i < 4; i++){
      int row = r0 + lq * 4 + i;
      float ea = fminf(__expf(accA[nb][i]), 60000.0f);   // fp16-safe; exact in ea>>1 limit
      eat[(lq * 4 + i) * 128 + col] = (_Float16)ea;
      _Float16 elh = (_Float16)fminf(__expf(accL[nb][i] + bb), 60000.0f);
      u16 sbf = ldstile[(lq * 4 + i) * 136 + col];
      _Float16 sh = (_Float16)b2f(sbf);                  // bf16 -> fp16 exact
      u32 elu = (u32)(*(const u16*)&elh);
      u32 shu = (u32)(*(const u16*)&sh);
      ghw[(size_t)row * 64 + (col & 63)] = elu | (shu << 16);
    }
  }
}

// coalesced eah writeback: 2 tiles x 16 rows x 128 fp16 = 8KB, 16B/thread x2.
__device__ __forceinline__ void eah_writeback(const _Float16* __restrict__ eat,
    _Float16* __restrict__ eah, int blk_r0, int tid){
  const uint4* src = (const uint4*)eat;       // 512 x 16B
  uint4* dst = (uint4*)(eah + (size_t)blk_r0 * 128);
  dst[tid]       = src[tid];
  dst[tid + 256] = src[tid + 256];
}

// init: states = tanh(obj@Wo + b) from raw objects; then eah/EL/S.
__global__ void __launch_bounds__(256) fused_init(const void* __restrict__ obj_raw,
    const int* __restrict__ flag, const u16* __restrict__ Wt,
    const float* __restrict__ biasf, _Float16* __restrict__ eah,
    u32* __restrict__ gat0, u32* __restrict__ gat1){
  __shared__ u16 lds[2][16 * 136];
  __shared__ _Float16 eat[2][16 * 128];
  const int lane = threadIdx.x & 63, wave = threadIdx.x >> 6;
  const int t = wave >> 1, ch = wave & 1, cofs = ch * 64;
  const int r0 = blockIdx.x * 32 + t * 16;
  const int lm = lane & 15, lq = lane >> 4;
  f32x4_t acc[4];
  #pragma unroll
  for (int i = 0; i < 4; i++) acc[i] = (f32x4_t){0.f, 0.f, 0.f, 0.f};
  if (*flag){
    const float* arow = (const float*)obj_raw + (size_t)(r0 + lm) * 128 + lq * 8;
    #pragma unroll
    for (int ks = 0; ks < 4; ks++){
      float4 fa = *(const float4*)(arow + ks * 32);
      float4 fb = *(const float4*)(arow + ks * 32 + 4);
      bf16x8_t a;
      a[0] = (short)f2bf(fa.x); a[1] = (short)f2bf(fa.y);
      a[2] = (short)f2bf(fa.z); a[3] = (short)f2bf(fa.w);
      a[4] = (short)f2bf(fb.x); a[5] = (short)f2bf(fb.y);
      a[6] = (short)f2bf(fb.z); a[7] = (short)f2bf(fb.w);
      #pragma unroll
      for (int nb = 0; nb < 4; nb++){
        bf16x8_t bfr = *(const bf16x8_t*)(Wt + (cofs + nb * 16 + lm) * 128 + ks * 32 + lq * 8);
        acc[nb] = __builtin_amdgcn_mfma_f32_16x16x32_bf16(a, bfr, acc[nb], 0, 0, 0);
      }
    }
  } else {
    gemm_tile4((const u16*)obj_raw + (size_t)(r0 + lm) * 128 + lq * 8, Wt, lm, lq, cofs, acc);
  }
  #pragma unroll
  for (int nb = 0; nb < 4; nb++){
    int col = cofs + nb * 16 + lm;
    float bb = biasf[col];
    #pragma unroll
    for (int i = 0; i < 4; i++)
      lds[t][(lq * 4 + i) * 136 + col] = f2bf(fast_tanh(acc[nb][i] + bb));
  }
  __syncthreads();
  phase2_awlaw4(&lds[t][0], Wt, biasf, lm, lq, cofs, r0, &eat[t][0], ch ? gat1 : gat0);
  __syncthreads();
  eah_writeback(&eat[0][0], eah, blockIdx.x * 32, threadIdx.x);
}

// mid: states = tanh(sa + lg@Wl + b); then eah/EL/S for next iter.
__global__ void __launch_bounds__(256) fused_mid(const u32* __restrict__ lgsa,
    const u16* __restrict__ Wt, const float* __restrict__ biasf,
    _Float16* __restrict__ eah, u32* __restrict__ gat0, u32* __restrict__ gat1){
  __shared__ u16 lds[2][16 * 136];
  __shared__ _Float16 eat[2][16 * 128];
  const int lane = threadIdx.x & 63, wave = threadIdx.x >> 6;
  const int t = wave >> 1, ch = wave & 1, cofs = ch * 64;
  const int r0 = blockIdx.x * 32 + t * 16;
  const int lm = lane & 15, lq = lane >> 4;
  f32x4_t acc[4];
  #pragma unroll
  for (int i = 0; i < 4; i++) acc[i] = (f32x4_t){0.f, 0.f, 0.f, 0.f};
  gemm_tile4_packed(lgsa + (size_t)(r0 + lm) * 128, Wt + 49152, lm, lq, cofs, acc);
  #pragma unroll
  for (int nb = 0; nb < 4; nb++){
    int col = cofs + nb * 16 + lm;
    float bb = biasf[col];
    #pragma unroll
    for (int i = 0; i < 4; i++){
      int row = r0 + lq * 4 + i;
      u32 v = lgsa[(size_t)row * 128 + col];
      u16 hb = (u16)(v >> 16);
      float sa = (float)(*(const _Float16*)&hb);
      lds[t][(lq * 4 + i) * 136 + col] = f2bf(fast_tanh(sa + acc[nb][i] + bb));
    }
  }
  __syncthreads();
  phase2_awlaw4(&lds[t][0], Wt, biasf, lm, lq, cofs, r0, &eat[t][0], ch ? gat1 : gat0);
  __syncthreads();
  eah_writeback(&eat[0][0], eah, blockIdx.x * 32, threadIdx.x);
}

// final: out = tanh(sa + lg@Wl + b), fp32 or bf16 per flag.
__global__ void __launch_bounds__(256) final_out(const u32* __restrict__ lgsa,
    const u16* __restrict__ Wt, const float* __restrict__ biasf,
    const int* __restrict__ flag, void* __restrict__ outp){
  const int lane = threadIdx.x & 63, wave = threadIdx.x >> 6;
  const int t = wave >> 1, ch = wave & 1, cofs = ch * 64;
  const int r0 = blockIdx.x * 32 + t * 16;
  const int lm = lane & 15, lq = lane >> 4;
  bool f32out = (*flag != 0);
  f32x4_t acc[4];
  #pragma unroll
  for (int i = 0; i < 4; i++) acc[i] = (f32x4_t){0.f, 0.f, 0.f, 0.f};
  gemm_tile4_packed(lgsa + (size_t)(r0 + lm) * 128, Wt + 49152, lm, lq, cofs, acc);
  #pragma unroll
  for (int nb = 0; nb < 4; nb++){
    int col = cofs + nb * 16 + lm;
    float bb = biasf[col];
    #pragma unroll
    for (int i = 0; i < 4; i++){
      int row = r0 + lq * 4 + i;
      u32 vv = lgsa[(size_t)row * 128 + col];
      u16 hb = (u16)(vv >> 16);
      float sa = (float)(*(const _Float16*)&hb);
      float v = fast_tanh(sa + acc[nb][i] + bb);
      if (f32out) ((float*)outp)[(size_t)row * 128 + col] = v;
      else        ((u16*)  outp)[(size_t)row * 128 + col] = f2bf(v);
    }
  }
}

// ---------------- edge gather: 4 edges per dwordx4 instruction ----------------
// lane = (q = lane>>4 edge slot, p = lane&15 channel quad). One dwordx4 load
// fetches channels p*4..p*4+3 of edge slot q's gat row -> 4 edges / instr.
// g = {S fp16 hi | EL fp16 lo}; 2 fma_mix per (edge,channel), fp32 accum.
__device__ __forceinline__ void acc_mix(u32 g, float one, float& a1, float& a2){
  asm("v_fma_mix_f32 %0, %2, %3, %0 op_sel:[0,0,0] op_sel_hi:[1,0,0]\n\t"
      "v_fma_mix_f32 %1, %2, %2, %1 op_sel:[0,1,0] op_sel_hi:[1,1,0]"
      : "+v"(a1), "+v"(a2)
      : "v"(g), "v"(one));
}

__device__ __forceinline__ uint4 gath4(const u32* __restrict__ gh, int d, int pofs){
  return *(const uint4*)((const char*)gh + (((size_t)(u32)d) << 8) + pofs);
}

#define ACC4(G) \
  acc_mix((G).x, one, s1a, s2a); acc_mix((G).y, one, s1b, s2b); \
  acc_mix((G).z, one, s1c, s2c); acc_mix((G).w, one, s1d, s2d);

__global__ void __launch_bounds__(256, 8) edge_kernel(const _Float16* __restrict__ eah,
    const u32* __restrict__ gat0, const u32* __restrict__ gat1,
    const int* __restrict__ row_start, const int* __restrict__ edge_dst,
    u32* __restrict__ lgsa){
  int blk = blockIdx.x;
  int xcd = blk & 7;
  int b = xcd >> 1, h = xcd & 1;
  int i = blk >> 3;                          // 0..2499
  int n = i * 4 + (int)(threadIdx.x >> 6);
  int node = b * NNODE + n;
  int lane = threadIdx.x & 63;
  int q = lane >> 4;                         // edge slot 0..3
  int p = lane & 15;                         // channel quad -> ch p*4..p*4+3
  int pofs = p << 4;                         // byte offset within gat row
  const u32* gh = (h ? gat1 : gat0) + (size_t)b * NNODE * 64;
  int e0 = __builtin_amdgcn_readfirstlane(row_start[b * (NNODE + 1) + n]);
  int e1 = __builtin_amdgcn_readfirstlane(row_start[b * (NNODE + 1) + n + 1]);
  const int* edq = edge_dst + (size_t)b * EDPAD + q;   // per-lane slot base

  // hoisted independent loads (used only at the end by q==0 lanes)
  uint2 eav = ((const uint2*)(eah + (size_t)node * 128 + h * 64))[p];
  uint4 self4 = *(const uint4*)((const char*)gh + (((size_t)(u32)n) << 8) + pofs);
  const float one = 1.0f;

  float s1a=0.f, s1b=0.f, s1c=0.f, s1d=0.f;
  float s2a=0.f, s2b=0.f, s2c=0.f, s2d=0.f;
  int ng = (e1 - e0) >> 3;                   // rows padded: len % 8 == 0
  if (ng){
    uint4 gA, gB, hA, hB;
    int dA, dB;
    int e = e0;
    // prologue: idx(grp0) -> gathers(grp0) -> idx(grp1)
    dA = edq[e]; dB = edq[e + 4];
    gA = gath4(gh, dA, pofs); gB = gath4(gh, dB, pofs);
    e += 8;
    dA = edq[e]; dB = edq[e + 4];            // overshoot-safe: reads stay in
    e += 8;                                  // edge_dst (used only if valid)
    // steady: 2 groups/iter ping-pong; gathers for k+1 issued before
    // consuming k; indices prefetched one group ahead.
    int k = 1;
    for (; k + 1 < ng; k += 2){
      hA = gath4(gh, dA, pofs); hB = gath4(gh, dB, pofs);
      dA = edq[e]; dB = edq[e + 4]; e += 8;
      ACC4(gA); ACC4(gB);
      gA = gath4(gh, dA, pofs); gB = gath4(gh, dB, pofs);
      dA = edq[e]; dB = edq[e + 4]; e += 8;
      ACC4(hA); ACC4(hB);
    }
    if (k < ng){                              // one trailing group in dA/dB
      hA = gath4(gh, dA, pofs); hB = gath4(gh, dB, pofs);
      ACC4(gA); ACC4(gB);
      ACC4(hA); ACC4(hB);
    } else {
      ACC4(gA); ACC4(gB);
    }
  }

  // butterfly reduce across the 4 edge slots (lanes differing in bits 4,5)
  s1a += __shfl_xor(s1a, 16, 64); s1a += __shfl_xor(s1a, 32, 64);
  s1b += __shfl_xor(s1b, 16, 64); s1b += __shfl_xor(s1b, 32, 64);
  s1c += __shfl_xor(s1c, 16, 64); s1c += __shfl_xor(s1c, 32, 64);
  s1d += __shfl_xor(s1d, 16, 64); s1d += __shfl_xor(s1d, 32, 64);
  s2a += __shfl_xor(s2a, 16, 64); s2a += __shfl_xor(s2a, 32, 64);
  s2b += __shfl_xor(s2b, 16, 64); s2b += __shfl_xor(s2b, 32, 64);
  s2c += __shfl_xor(s2c, 16, 64); s2c += __shfl_xor(s2c, 32, 64);
  s2d += __shfl_xor(s2d, 16, 64); s2d += __shfl_xor(s2d, 32, 64);

  if (q == 0){
    union { uint2 u; _Float16 f[4]; } ec; ec.u = eav;
    union { uint4 u; u32 w[4]; } sv; sv.u = self4;
    float S1[4] = {s1a, s1b, s1c, s1d};
    float S2[4] = {s2a, s2b, s2c, s2d};
    u32 out[4];
    #pragma unroll
    for (int k2 = 0; k2 < 4; k2++){
      float ea = (float)ec.f[k2];
      float inv = __builtin_amdgcn_rcpf(fmaf(ea, S1[k2], 1.0f));
      float lg = ea * S2[k2] * inv;
      u16 hb = (u16)(sv.w[k2] >> 16);
      float s_self = (float)(*(const _Float16*)&hb);
      _Float16 hs = (_Float16)(s_self * inv);
      out[k2] = (u32)f2bf(lg) | ((u32)(*(const u16*)&hs) << 16);
    }
    *(uint4*)(lgsa + (size_t)node * 128 + h * 64 + (p << 2)) = *(const uint4*)out;
  }
}

// ---------------- host launcher ----------------------------------------------
extern "C" void kernel_launch(void* const* d_in, const int* in_sizes, int n_in,
                              void* d_out, int out_size, void* d_ws, size_t ws_size,
                              hipStream_t stream){
  (void)in_sizes; (void)n_in; (void)ws_size; (void)out_size;
  const void* objects = d_in[0];
  const void* Wo      = d_in[1];
  const void* Wa      = d_in[2];
  const void* Wla     = d_in[3];
  const void* attn_b  = d_in[4];
  const void* Wl      = d_in[5];
  const void* state_b = d_in[6];
  const int*  conn    = (const int*)d_in[7];

  char* base = (char*)d_ws;
  size_t off = 0;
  auto alloc = [&](size_t bytes) -> char* {
    char* p = base + off;
    off = (off + bytes + 255) & ~(size_t)255;
    return p;
  };
  int*      flag      = (int*)     alloc(256);
  u16*      Wt        = (u16*)     alloc((size_t)4 * 16384 * 2);
  float*    biasf     = (float*)   alloc(256 * 4);
  _Float16* eah       = (_Float16*)alloc((size_t)MROWS * 128 * 2);       // exp(aW) fp16
  u32*      gat0      = (u32*)     alloc((size_t)(MROWS + 4) * 64 * 4);  // ch 0-63 {S|EL} + 4 zero rows
  u32*      gat1      = (u32*)     alloc((size_t)(MROWS + 4) * 64 * 4);  // ch 64-127 + 4 zero rows
  u32*      lgsa      = (u32*)     alloc((size_t)MROWS * 128 * 4);       // {lg bf16 | sa fp16}
  u16*      partial   = (u16*)     alloc((size_t)BATCH * NCHUNK * PADN * 2);
  int*      row_start = (int*)     alloc((size_t)BATCH * (NNODE + 1) * 4);
  int*      edge_dst  = (int*)     alloc((size_t)BATCH * EDPAD * 4);     // padded CSR
  int*      deg       = (int*)     alloc((size_t)MROWS * 4);
  int*      bsum      = (int*)     alloc(160 * 4);
  int*      boff      = (int*)     alloc(160 * 4);

  detect_dtype<<<1, 256, 0, stream>>>((const u32*)objects, flag);
  prep_weights<<<257, 256, 0, stream>>>(Wo, Wa, Wla, Wl, attn_b, state_b, flag, Wt, biasf);

  csr_hist<<<256, 256, 0, stream>>>(conn, partial);
  csr_colscan<<<160, 256, 0, stream>>>(partial, row_start, bsum, deg);
  scanB<<<1, 256, 0, stream>>>(bsum, boff, row_start);
  scanC<<<160, 256, 0, stream>>>(row_start, boff);
  csr_fill<<<256, 256, 0, stream>>>(conn, partial, row_start, edge_dst);
  pad_fill<<<160, 256, 0, stream>>>(row_start, deg, edge_dst);
  zero_sent<<<1, 256, 0, stream>>>(gat0, gat1);

  fused_init<<<MROWS / 32, 256, 0, stream>>>(objects, flag, Wt, biasf, eah, gat0, gat1);
  edge_kernel<<<MROWS / 2, 256, 0, stream>>>(eah, gat0, gat1, row_start, edge_dst, lgsa);
  fused_mid<<<MROWS / 32, 256, 0, stream>>>(lgsa, Wt, biasf, eah, gat0, gat1);
  edge_kernel<<<MROWS / 2, 256, 0, stream>>>(eah, gat0, gat1, row_start, edge_dst, lgsa);
  fused_mid<<<MROWS / 32, 256, 0, stream>>>(lgsa, Wt, biasf, eah, gat0, gat1);
  edge_kernel<<<MROWS / 2, 256, 0, stream>>>(eah, gat0, gat1, row_start, edge_dst, lgsa);
  final_out<<<MROWS / 32, 256, 0, stream>>>(lgsa, Wt, biasf, flag, d_out);
}

// Round 7
// 355.905 us; speedup vs baseline: 1.1111x; 1.1111x over previous
//
#include <hip/hip_runtime.h>
#include <hip/hip_bf16.h>

// AttentiveGraph: B=4, N=10000, E=160000, C=F=128, 3 iterations.
// R17: R15/R16's wide-lane gather REGRESSED (VALU-busy 16->32us: per-lane
// 64-bit address math + vector index loads replaced scalar/SALU work).
// Revert edge_kernel to R14's measured-best scalar ping-pong, plus:
// (a) 128-thread edge blocks (2 nodes/block, grid 40000): finer scheduling
//     granularity cuts intra-block degree imbalance -> higher waves/CU;
// (b) 3 fewer dispatches: detect_dtype folded into prep_weights (per-block
//     local detect, block 0 publishes flag), scanB folded into scanC
//     (local bsum prefix sums), zero_sent folded into pad_fill (block 0).
// CSR pad-to-8 + sentinel zero rows kept. fma_mix accumulate kept.
// Fused GEMM kernels, gat/lgsa formats, eah staging unchanged.

#define BATCH 4
#define NNODE 10000
#define NEDGE 160000
#define TWOE  (2*NEDGE)
#define MROWS (BATCH*NNODE)   // 40000
#define NCHUNK 64
#define CHUNKE (NEDGE/NCHUNK) // 2500
#define PADN  10240
#define EDPAD (TWOE + 8*NNODE) // 400000: padded edge capacity per batch

typedef unsigned short u16;
typedef unsigned int   u32;
typedef __attribute__((ext_vector_type(8))) short bf16x8_t;
typedef __attribute__((ext_vector_type(4))) float f32x4_t;

__device__ __forceinline__ float b2f(u16 h){ return __uint_as_float(((u32)h) << 16); }
__device__ __forceinline__ u16 f2bf(float f){
  u32 u = __float_as_uint(f);
  return (u16)((u + 0x7fffu + ((u >> 16) & 1u)) >> 16);   // RNE
}
__device__ __forceinline__ float fast_tanh(float x){
  float e = __expf(2.0f * x);
  return fmaf(-2.0f, __builtin_amdgcn_rcpf(e + 1.0f), 1.0f);
}

// ---------------- weights prep (with fused dtype probe) -----------------------
// Each block re-derives the storage dtype from objects' first 1KB (cheap,
// uniform result); block 0 publishes flag for fused_init/final_out.
__global__ void prep_weights(const void* __restrict__ objects,
                             const void* __restrict__ Wo, const void* __restrict__ Wa,
                             const void* __restrict__ Wla, const void* __restrict__ Wl,
                             const void* __restrict__ ab, const void* __restrict__ sb,
                             int* __restrict__ flag, u16* __restrict__ Wt,
                             float* __restrict__ biasf){
  __shared__ int zc, hc;
  if (threadIdx.x == 0){ zc = 0; hc = 0; }
  __syncthreads();
  const u32* objw = (const u32*)objects;
  int z = 0, hcnt = 0;
  for (int i = threadIdx.x; i < 1024; i += 256){
    u32 lo = objw[i] & 0xffffu;
    if (lo == 0) z++;
    if (((lo >> 7) & 0xffu) >= 160u) hcnt++;
  }
  atomicAdd(&zc, z); atomicAdd(&hc, hcnt);
  __syncthreads();
  bool f = (hc > 0 || zc > 512);              // 1 = fp32 storage
  if (blockIdx.x == 0 && threadIdx.x == 0) *flag = f ? 1 : 0;

  int idx = blockIdx.x * 256 + threadIdx.x;
  if (idx < 65536){
    int m = idx >> 14, k = (idx >> 7) & 127, c = idx & 127;
    const void* src = (m == 0) ? Wo : (m == 1) ? Wa : (m == 2) ? Wla : Wl;
    u16 h = f ? f2bf(((const float*)src)[k * 128 + c]) : ((const u16*)src)[k * 128 + c];
    Wt[m * 16384 + c * 128 + k] = h;
  } else {
    int t = idx - 65536;
    const void* src = (t < 128) ? sb : ab;
    int i = t & 127;
    biasf[t] = f ? ((const float*)src)[i] : b2f(((const u16*)src)[i]);
  }
}

// ---------------- CSR build: 3-phase chunked histogram ------------------------
__device__ __forceinline__ void chunk_of(int blk, int& b, int& c){
  int xcd = blk & 7;
  b = xcd >> 1;
  c = ((blk >> 3) << 1) | (xcd & 1);           // 0..63
}

__global__ void __launch_bounds__(256) csr_hist(const int* __restrict__ conn,
                                                u16* __restrict__ partial){
  int b, c; chunk_of(blockIdx.x, b, c);
  __shared__ u32 hist[NNODE];
  for (int n = threadIdx.x; n < NNODE; n += 256) hist[n] = 0;
  __syncthreads();
  const int2* cp = (const int2*)conn + (size_t)b * NEDGE + c * CHUNKE;
  for (int i = threadIdx.x; i < CHUNKE; i += 256){
    int2 e = cp[i];
    atomicAdd(&hist[e.x], 1);
    atomicAdd(&hist[e.y], 1);
  }
  __syncthreads();
  u16* prow = partial + (size_t)(b * NCHUNK + c) * PADN;
  for (int n = threadIdx.x; n < NNODE; n += 256) prow[n] = (u16)hist[n];
}

// prefix over chunks per node (true offsets stored back), then block-scan of
// PADDED row lengths (multiple of 8); deg[] keeps true degree for pad_fill.
__global__ void __launch_bounds__(256) csr_colscan(u16* __restrict__ partial,
    int* __restrict__ row_start, int* __restrict__ bsum, int* __restrict__ deg){
  int b = blockIdx.x / 40, w = blockIdx.x % 40;
  int n = w * 256 + threadIdx.x;
  u32 run = 0;
  if (n < NNODE){
    #pragma unroll 8
    for (int c = 0; c < NCHUNK; c++){
      size_t idx = (size_t)(b * NCHUNK + c) * PADN + n;
      u32 v = partial[idx];
      partial[idx] = (u16)run;
      run += v;
    }
  }
  u32 pad = (run + 7u) & ~7u;
  __shared__ u32 buf[256];
  buf[threadIdx.x] = pad;
  __syncthreads();
  for (int off = 1; off < 256; off <<= 1){
    u32 x = (threadIdx.x >= (unsigned)off) ? buf[threadIdx.x - off] : 0;
    __syncthreads();
    buf[threadIdx.x] += x;
    __syncthreads();
  }
  u32 incl = buf[threadIdx.x];
  if (n < NNODE){
    row_start[b * (NNODE + 1) + n] = (int)(incl - pad);  // window-local padded
    deg[b * NNODE + n] = (int)run;
  }
  if (threadIdx.x == 255) bsum[blockIdx.x] = (int)incl;
}

// scanC with scanB folded in: each block locally prefix-sums its batch's bsum
// (<=39 uniform scalar loads); block j==39 also writes the padded batch total.
__global__ void scanC(int* __restrict__ row_start, const int* __restrict__ bsum){
  int b = blockIdx.x / 40, j = blockIdx.x % 40;
  int n = j * 256 + threadIdx.x;
  int off = 0;
  for (int q = b * 40; q < b * 40 + j; q++) off += bsum[q];
  if (n < NNODE) row_start[b * (NNODE + 1) + n] += off;
  if (j == 39 && threadIdx.x == 0)
    row_start[b * (NNODE + 1) + NNODE] = off + bsum[b * 40 + 39];
}

__global__ void __launch_bounds__(256) csr_fill(const int* __restrict__ conn,
    const u16* __restrict__ partial, const int* __restrict__ row_start,
    int* __restrict__ edge_dst){
  int b, c; chunk_of(blockIdx.x, b, c);
  __shared__ u32 cur[NNODE];
  const u16* prow = partial + (size_t)(b * NCHUNK + c) * PADN;
  const int* rs = row_start + b * (NNODE + 1);
  for (int n = threadIdx.x; n < NNODE; n += 256) cur[n] = (u32)rs[n] + prow[n];
  __syncthreads();
  const int2* cp = (const int2*)conn + (size_t)b * NEDGE + c * CHUNKE;
  int* edb = edge_dst + (size_t)b * EDPAD;
  for (int i = threadIdx.x; i < CHUNKE; i += 256){
    int2 e = cp[i];
    u32 p1 = atomicAdd(&cur[e.x], 1); edb[p1] = e.y;
    u32 p2 = atomicAdd(&cur[e.y], 1); edb[p2] = e.x;
  }
}

// fill pad slots [rs[n]+deg, rs[n+1]) with the batch's sentinel local index
// (sentinel local d maps to global gat row 40000+b: d = 40000 - 9999*b).
// Block 0 also zeroes the 4 sentinel rows in both gat halves (zero_sent fold).
__global__ void pad_fill(const int* __restrict__ row_start,
                         const int* __restrict__ deg, int* __restrict__ edge_dst,
                         u32* __restrict__ g0, u32* __restrict__ g1){
  if (blockIdx.x == 0){
    size_t base = (size_t)MROWS * 64;
    g0[base + threadIdx.x] = 0;
    g1[base + threadIdx.x] = 0;
  }
  int b = blockIdx.x / 40, j = blockIdx.x % 40;
  int n = j * 256 + threadIdx.x;
  if (n >= NNODE) return;
  const int* rs = row_start + b * (NNODE + 1);
  int s = rs[n] + deg[b * NNODE + n];
  int epad = rs[n + 1];
  int sent = 40000 - 9999 * b;
  int* edb = edge_dst + (size_t)b * EDPAD;
  for (int p = s; p < epad; p++) edb[p] = sent;
}

// ---------------- MFMA helpers (wave = 16 rows x 64 cols) ---------------------
__device__ __forceinline__ void gemm_tile4(const u16* __restrict__ arow,
    const u16* __restrict__ wt, int lm, int lq, int cofs, f32x4_t acc[4]){
  #pragma unroll
  for (int ks = 0; ks < 4; ks++){
    bf16x8_t a = *(const bf16x8_t*)(arow + ks * 32);
    #pragma unroll
    for (int nb = 0; nb < 4; nb++){
      bf16x8_t bfr = *(const bf16x8_t*)(wt + (cofs + nb * 16 + lm) * 128 + ks * 32 + lq * 8);
      acc[nb] = __builtin_amdgcn_mfma_f32_16x16x32_bf16(a, bfr, acc[nb], 0, 0, 0);
    }
  }
}

// A-frag from packed lgsa (lg = low u16 of each u32). Lrow = row base ONLY.
__device__ __forceinline__ void gemm_tile4_packed(const u32* __restrict__ Lrow,
    const u16* __restrict__ wt, int lm, int lq, int cofs, f32x4_t acc[4]){
  #pragma unroll
  for (int ks = 0; ks < 4; ks++){
    uint4 wa = *(const uint4*)(Lrow + ks * 32 + lq * 8);
    uint4 wb = *(const uint4*)(Lrow + ks * 32 + lq * 8 + 4);
    bf16x8_t a;
    a[0] = (short)wa.x; a[1] = (short)wa.y; a[2] = (short)wa.z; a[3] = (short)wa.w;
    a[4] = (short)wb.x; a[5] = (short)wb.y; a[6] = (short)wb.z; a[7] = (short)wb.w;
    #pragma unroll
    for (int nb = 0; nb < 4; nb++){
      bf16x8_t bfr = *(const bf16x8_t*)(wt + (cofs + nb * 16 + lm) * 128 + ks * 32 + lq * 8);
      acc[nb] = __builtin_amdgcn_mfma_f32_16x16x32_bf16(a, bfr, acc[nb], 0, 0, 0);
    }
  }
}

// phase 2: states tile (LDS, A-layout) -> gat {S fp16 hi | EL fp16 lo} u32
// stores (full-line) + ea fp16 into LDS tile eat (coalesced global store done
// by caller).
__device__ __forceinline__ void phase2_awlaw4(const u16* __restrict__ ldstile,
    const u16* __restrict__ Wt, const float* __restrict__ biasf,
    int lm, int lq, int cofs, int r0, _Float16* __restrict__ eat,
    u32* __restrict__ ghw){
  const u16* Wta  = Wt + 16384;
  const u16* Wtla = Wt + 32768;
  const u16* ldsrow = ldstile + lm * 136 + lq * 8;
  f32x4_t accA[4], accL[4];
  #pragma unroll
  for (int i = 0; i < 4; i++){ accA[i] = (f32x4_t){0.f,0.f,0.f,0.f}; accL[i] = (f32x4_t){0.f,0.f,0.f,0.f}; }
  #pragma unroll
  for (int ks = 0; ks < 4; ks++){
    bf16x8_t a = *(const bf16x8_t*)(ldsrow + ks * 32);
    #pragma unroll
    for (int nb = 0; nb < 4; nb++){
      bf16x8_t ba = *(const bf16x8_t*)(Wta  + (cofs + nb * 16 + lm) * 128 + ks * 32 + lq * 8);
      bf16x8_t bl = *(const bf16x8_t*)(Wtla + (cofs + nb * 16 + lm) * 128 + ks * 32 + lq * 8);
      accA[nb] = __builtin_amdgcn_mfma_f32_16x16x32_bf16(a, ba, accA[nb], 0, 0, 0);
      accL[nb] = __builtin_amdgcn_mfma_f32_16x16x32_bf16(a, bl, accL[nb], 0, 0, 0);
    }
  }
  #pragma unroll
  for (int nb = 0; nb < 4; nb++){
    int col = cofs + nb * 16 + lm;
    float bb = biasf[128 + col];
    #pragma unroll
    for (int i = 0; i < 4; i++){
      int row = r0 + lq * 4 + i;
      float ea = fminf(__expf(accA[nb][i]), 60000.0f);   // fp16-safe; exact in ea>>1 limit
      eat[(lq * 4 + i) * 128 + col] = (_Float16)ea;
      _Float16 elh = (_Float16)fminf(__expf(accL[nb][i] + bb), 60000.0f);
      u16 sbf = ldstile[(lq * 4 + i) * 136 + col];
      _Float16 sh = (_Float16)b2f(sbf);                  // bf16 -> fp16 exact
      u32 elu = (u32)(*(const u16*)&elh);
      u32 shu = (u32)(*(const u16*)&sh);
      ghw[(size_t)row * 64 + (col & 63)] = elu | (shu << 16);
    }
  }
}

// coalesced eah writeback: 2 tiles x 16 rows x 128 fp16 = 8KB, 16B/thread x2.
__device__ __forceinline__ void eah_writeback(const _Float16* __restrict__ eat,
    _Float16* __restrict__ eah, int blk_r0, int tid){
  const uint4* src = (const uint4*)eat;       // 512 x 16B
  uint4* dst = (uint4*)(eah + (size_t)blk_r0 * 128);
  dst[tid]       = src[tid];
  dst[tid + 256] = src[tid + 256];
}

// init: states = tanh(obj@Wo + b) from raw objects; then eah/EL/S.
__global__ void __launch_bounds__(256) fused_init(const void* __restrict__ obj_raw,
    const int* __restrict__ flag, const u16* __restrict__ Wt,
    const float* __restrict__ biasf, _Float16* __restrict__ eah,
    u32* __restrict__ gat0, u32* __restrict__ gat1){
  __shared__ u16 lds[2][16 * 136];
  __shared__ _Float16 eat[2][16 * 128];
  const int lane = threadIdx.x & 63, wave = threadIdx.x >> 6;
  const int t = wave >> 1, ch = wave & 1, cofs = ch * 64;
  const int r0 = blockIdx.x * 32 + t * 16;
  const int lm = lane & 15, lq = lane >> 4;
  f32x4_t acc[4];
  #pragma unroll
  for (int i = 0; i < 4; i++) acc[i] = (f32x4_t){0.f, 0.f, 0.f, 0.f};
  if (*flag){
    const float* arow = (const float*)obj_raw + (size_t)(r0 + lm) * 128 + lq * 8;
    #pragma unroll
    for (int ks = 0; ks < 4; ks++){
      float4 fa = *(const float4*)(arow + ks * 32);
      float4 fb = *(const float4*)(arow + ks * 32 + 4);
      bf16x8_t a;
      a[0] = (short)f2bf(fa.x); a[1] = (short)f2bf(fa.y);
      a[2] = (short)f2bf(fa.z); a[3] = (short)f2bf(fa.w);
      a[4] = (short)f2bf(fb.x); a[5] = (short)f2bf(fb.y);
      a[6] = (short)f2bf(fb.z); a[7] = (short)f2bf(fb.w);
      #pragma unroll
      for (int nb = 0; nb < 4; nb++){
        bf16x8_t bfr = *(const bf16x8_t*)(Wt + (cofs + nb * 16 + lm) * 128 + ks * 32 + lq * 8);
        acc[nb] = __builtin_amdgcn_mfma_f32_16x16x32_bf16(a, bfr, acc[nb], 0, 0, 0);
      }
    }
  } else {
    gemm_tile4((const u16*)obj_raw + (size_t)(r0 + lm) * 128 + lq * 8, Wt, lm, lq, cofs, acc);
  }
  #pragma unroll
  for (int nb = 0; nb < 4; nb++){
    int col = cofs + nb * 16 + lm;
    float bb = biasf[col];
    #pragma unroll
    for (int i = 0; i < 4; i++)
      lds[t][(lq * 4 + i) * 136 + col] = f2bf(fast_tanh(acc[nb][i] + bb));
  }
  __syncthreads();
  phase2_awlaw4(&lds[t][0], Wt, biasf, lm, lq, cofs, r0, &eat[t][0], ch ? gat1 : gat0);
  __syncthreads();
  eah_writeback(&eat[0][0], eah, blockIdx.x * 32, threadIdx.x);
}

// mid: states = tanh(sa + lg@Wl + b); then eah/EL/S for next iter.
__global__ void __launch_bounds__(256) fused_mid(const u32* __restrict__ lgsa,
    const u16* __restrict__ Wt, const float* __restrict__ biasf,
    _Float16* __restrict__ eah, u32* __restrict__ gat0, u32* __restrict__ gat1){
  __shared__ u16 lds[2][16 * 136];
  __shared__ _Float16 eat[2][16 * 128];
  const int lane = threadIdx.x & 63, wave = threadIdx.x >> 6;
  const int t = wave >> 1, ch = wave & 1, cofs = ch * 64;
  const int r0 = blockIdx.x * 32 + t * 16;
  const int lm = lane & 15, lq = lane >> 4;
  f32x4_t acc[4];
  #pragma unroll
  for (int i = 0; i < 4; i++) acc[i] = (f32x4_t){0.f, 0.f, 0.f, 0.f};
  gemm_tile4_packed(lgsa + (size_t)(r0 + lm) * 128, Wt + 49152, lm, lq, cofs, acc);
  #pragma unroll
  for (int nb = 0; nb < 4; nb++){
    int col = cofs + nb * 16 + lm;
    float bb = biasf[col];
    #pragma unroll
    for (int i = 0; i < 4; i++){
      int row = r0 + lq * 4 + i;
      u32 v = lgsa[(size_t)row * 128 + col];
      u16 hb = (u16)(v >> 16);
      float sa = (float)(*(const _Float16*)&hb);
      lds[t][(lq * 4 + i) * 136 + col] = f2bf(fast_tanh(sa + acc[nb][i] + bb));
    }
  }
  __syncthreads();
  phase2_awlaw4(&lds[t][0], Wt, biasf, lm, lq, cofs, r0, &eat[t][0], ch ? gat1 : gat0);
  __syncthreads();
  eah_writeback(&eat[0][0], eah, blockIdx.x * 32, threadIdx.x);
}

// final: out = tanh(sa + lg@Wl + b), fp32 or bf16 per flag.
__global__ void __launch_bounds__(256) final_out(const u32* __restrict__ lgsa,
    const u16* __restrict__ Wt, const float* __restrict__ biasf,
    const int* __restrict__ flag, void* __restrict__ outp){
  const int lane = threadIdx.x & 63, wave = threadIdx.x >> 6;
  const int t = wave >> 1, ch = wave & 1, cofs = ch * 64;
  const int r0 = blockIdx.x * 32 + t * 16;
  const int lm = lane & 15, lq = lane >> 4;
  bool f32out = (*flag != 0);
  f32x4_t acc[4];
  #pragma unroll
  for (int i = 0; i < 4; i++) acc[i] = (f32x4_t){0.f, 0.f, 0.f, 0.f};
  gemm_tile4_packed(lgsa + (size_t)(r0 + lm) * 128, Wt + 49152, lm, lq, cofs, acc);
  #pragma unroll
  for (int nb = 0; nb < 4; nb++){
    int col = cofs + nb * 16 + lm;
    float bb = biasf[col];
    #pragma unroll
    for (int i = 0; i < 4; i++){
      int row = r0 + lq * 4 + i;
      u32 vv = lgsa[(size_t)row * 128 + col];
      u16 hb = (u16)(vv >> 16);
      float sa = (float)(*(const _Float16*)&hb);
      float v = fast_tanh(sa + acc[nb][i] + bb);
      if (f32out) ((float*)outp)[(size_t)row * 128 + col] = v;
      else        ((u16*)  outp)[(size_t)row * 128 + col] = f2bf(v);
    }
  }
}

// ---------------- edge gather: half-channel split, 1 wave/node ----------------
// g = {S fp16 hi | EL fp16 lo}. Exactly 2 VALU ops per edge:
//   a1 = f16lo(g)*one + a1 ; a2 = f16lo(g)*f16hi(g) + a2  (fp32 accum)
__device__ __forceinline__ void acc_mix(u32 g, float one, float& a1, float& a2){
  asm("v_fma_mix_f32 %0, %2, %3, %0 op_sel:[0,0,0] op_sel_hi:[1,0,0]\n\t"
      "v_fma_mix_f32 %1, %2, %2, %1 op_sel:[0,1,0] op_sel_hi:[1,1,0]"
      : "+v"(a1), "+v"(a2)
      : "v"(g), "v"(one));
}

// scalar-addressed gather: d uniform (SGPR) -> saddr-form global_load, zero
// VALU address math (row pointer is scalar; vaddr = c*4, loop-invariant).
__device__ __forceinline__ u32 gath1(const u32* __restrict__ gh, int d, int c){
  const u32* p = (const u32*)((const char*)gh + ((size_t)(u32)d << 8));
  return p[c];
}

// 128-thread blocks: 2 nodes/block -> finer scheduling granularity than R14's
// 4-wave blocks (less intra-block degree imbalance, more resident waves).
__global__ void __launch_bounds__(128, 8) edge_kernel(const _Float16* __restrict__ eah,
    const u32* __restrict__ gat0, const u32* __restrict__ gat1,
    const int* __restrict__ row_start, const int* __restrict__ edge_dst,
    u32* __restrict__ lgsa){
  int blk = blockIdx.x;
  int xcd = blk & 7;
  int b = xcd >> 1, h = xcd & 1;
  int i = blk >> 3;                          // 0..4999
  int n = i * 2 + (int)(threadIdx.x >> 6);
  int node = b * NNODE + n;
  int c = threadIdx.x & 63;
  const u32* gh = (h ? gat1 : gat0) + (size_t)b * NNODE * 64;
  int e0 = __builtin_amdgcn_readfirstlane(row_start[b * (NNODE + 1) + n]);
  int e1 = __builtin_amdgcn_readfirstlane(row_start[b * (NNODE + 1) + n + 1]);
  const int* ed = edge_dst + (size_t)b * EDPAD;

  // independent loads issued before the gather pipeline
  float ea = (float)eah[(size_t)node * 128 + h * 64 + c];
  u32 self = gh[((size_t)n << 6) + c];
  const float one = 1.0f;

  float s1 = 0.f, s2 = 0.f, t1 = 0.f, t2 = 0.f;
  int ng = (e1 - e0) >> 3;                   // rows padded: len % 8 == 0
  if (ng){
    int dB[8]; u32 g[8], gn[8];
    int e = e0;
    // prologue: idx(g0) -> gather(g0) -> idx(g1)
    { const int* ep = ed + e;
      #pragma unroll
      for (int j = 0; j < 8; j++) dB[j] = __builtin_amdgcn_readfirstlane(ep[j]); }
    #pragma unroll
    for (int j = 0; j < 8; j++) g[j] = gath1(gh, dB[j], c);
    e += 8;
    { const int* ep = ed + e;                // overshoot-safe: within workspace
      #pragma unroll
      for (int j = 0; j < 8; j++) dB[j] = __builtin_amdgcn_readfirstlane(ep[j]); }
    e += 8;
    // steady state, 2 groups per iteration, ping-pong (no register copies):
    // gather k+1 issued before consuming k; indices one group ahead.
    int k = 1;
    for (; k + 1 < ng; k += 2){
      #pragma unroll
      for (int j = 0; j < 8; j++) gn[j] = gath1(gh, dB[j], c);
      { const int* ep = ed + e;
        #pragma unroll
        for (int j = 0; j < 8; j++) dB[j] = __builtin_amdgcn_readfirstlane(ep[j]); }
      e += 8;
      #pragma unroll
      for (int j = 0; j < 8; j++) acc_mix(g[j], one, (j & 1) ? t1 : s1, (j & 1) ? t2 : s2);
      #pragma unroll
      for (int j = 0; j < 8; j++) g[j] = gath1(gh, dB[j], c);
      { const int* ep = ed + e;
        #pragma unroll
        for (int j = 0; j < 8; j++) dB[j] = __builtin_amdgcn_readfirstlane(ep[j]); }
      e += 8;
      #pragma unroll
      for (int j = 0; j < 8; j++) acc_mix(gn[j], one, (j & 1) ? t1 : s1, (j & 1) ? t2 : s2);
    }
    if (k < ng){                              // one trailing group in dB
      #pragma unroll
      for (int j = 0; j < 8; j++) gn[j] = gath1(gh, dB[j], c);
      #pragma unroll
      for (int j = 0; j < 8; j++) acc_mix(g[j], one, (j & 1) ? t1 : s1, (j & 1) ? t2 : s2);
      #pragma unroll
      for (int j = 0; j < 8; j++) acc_mix(gn[j], one, (j & 1) ? t1 : s1, (j & 1) ? t2 : s2);
    } else {
      #pragma unroll
      for (int j = 0; j < 8; j++) acc_mix(g[j], one, (j & 1) ? t1 : s1, (j & 1) ? t2 : s2);
    }
  }

  s1 += t1; s2 += t2;
  float inv = __builtin_amdgcn_rcpf(fmaf(ea, s1, 1.0f));
  float lg = ea * s2 * inv;
  u16 hb = (u16)(self >> 16);
  float s_self = (float)(*(const _Float16*)&hb);
  _Float16 hs = (_Float16)(s_self * inv);
  u32 pk = (u32)f2bf(lg) | ((u32)(*(const u16*)&hs) << 16);
  lgsa[(size_t)node * 128 + h * 64 + c] = pk;
}

// ---------------- host launcher ----------------------------------------------
extern "C" void kernel_launch(void* const* d_in, const int* in_sizes, int n_in,
                              void* d_out, int out_size, void* d_ws, size_t ws_size,
                              hipStream_t stream){
  (void)in_sizes; (void)n_in; (void)ws_size; (void)out_size;
  const void* objects = d_in[0];
  const void* Wo      = d_in[1];
  const void* Wa      = d_in[2];
  const void* Wla     = d_in[3];
  const void* attn_b  = d_in[4];
  const void* Wl      = d_in[5];
  const void* state_b = d_in[6];
  const int*  conn    = (const int*)d_in[7];

  char* base = (char*)d_ws;
  size_t off = 0;
  auto alloc = [&](size_t bytes) -> char* {
    char* p = base + off;
    off = (off + bytes + 255) & ~(size_t)255;
    return p;
  };
  int*      flag      = (int*)     alloc(256);
  u16*      Wt        = (u16*)     alloc((size_t)4 * 16384 * 2);
  float*    biasf     = (float*)   alloc(256 * 4);
  _Float16* eah       = (_Float16*)alloc((size_t)MROWS * 128 * 2);       // exp(aW) fp16
  u32*      gat0      = (u32*)     alloc((size_t)(MROWS + 4) * 64 * 4);  // ch 0-63 {S|EL} + 4 zero rows
  u32*      gat1      = (u32*)     alloc((size_t)(MROWS + 4) * 64 * 4);  // ch 64-127 + 4 zero rows
  u32*      lgsa      = (u32*)     alloc((size_t)MROWS * 128 * 4);       // {lg bf16 | sa fp16}
  u16*      partial   = (u16*)     alloc((size_t)BATCH * NCHUNK * PADN * 2);
  int*      row_start = (int*)     alloc((size_t)BATCH * (NNODE + 1) * 4);
  int*      edge_dst  = (int*)     alloc((size_t)BATCH * EDPAD * 4);     // padded CSR
  int*      deg       = (int*)     alloc((size_t)MROWS * 4);
  int*      bsum      = (int*)     alloc(160 * 4);

  prep_weights<<<257, 256, 0, stream>>>(objects, Wo, Wa, Wla, Wl, attn_b, state_b,
                                        flag, Wt, biasf);

  csr_hist<<<256, 256, 0, stream>>>(conn, partial);
  csr_colscan<<<160, 256, 0, stream>>>(partial, row_start, bsum, deg);
  scanC<<<160, 256, 0, stream>>>(row_start, bsum);
  csr_fill<<<256, 256, 0, stream>>>(conn, partial, row_start, edge_dst);
  pad_fill<<<160, 256, 0, stream>>>(row_start, deg, edge_dst, gat0, gat1);

  fused_init<<<MROWS / 32, 256, 0, stream>>>(objects, flag, Wt, biasf, eah, gat0, gat1);
  edge_kernel<<<MROWS, 128, 0, stream>>>(eah, gat0, gat1, row_start, edge_dst, lgsa);
  fused_mid<<<MROWS / 32, 256, 0, stream>>>(lgsa, Wt, biasf, eah, gat0, gat1);
  edge_kernel<<<MROWS, 128, 0, stream>>>(eah, gat0, gat1, row_start, edge_dst, lgsa);
  fused_mid<<<MROWS / 32, 256, 0, stream>>>(lgsa, Wt, biasf, eah, gat0, gat1);
  edge_kernel<<<MROWS, 128, 0, stream>>>(eah, gat0, gat1, row_start, edge_dst, lgsa);
  final_out<<<MROWS / 32, 256, 0, stream>>>(lgsa, Wt, biasf, flag, d_out);
}